// Round 3
// baseline (584.874 us; speedup 1.0000x reference)
//
#include <hip/hip_runtime.h>
#include <hip/hip_bf16.h>

typedef __attribute__((ext_vector_type(8))) short s16x8;
typedef __attribute__((ext_vector_type(4))) float f32x4;
typedef __attribute__((ext_vector_type(4))) unsigned short us4;

#define DI __device__ __forceinline__

DI float b2f(unsigned short u){ union{float f; unsigned int i;} v; v.i = ((unsigned int)u)<<16; return v.f; }
DI unsigned short f2b(float f){ union{float f; unsigned int i;} v; v.f = f; unsigned int r = v.i + 0x7FFF + ((v.i>>16)&1u); return (unsigned short)(r>>16); }
DI float geluf(float x){ return 0.5f*x*(1.f + erff(x*0.70710678118654752f)); }
DI float sigmf(float x){ return 1.f/(1.f + expf(-x)); }

#define MFMA(a,b,c) __builtin_amdgcn_mfma_f32_16x16x32_bf16((a),(b),(c),0,0,0)

// ---------------- repack W (K x M, row-major fp32) into bf16 MFMA A-frag layout ----------------
__global__ __launch_bounds__(256) void k_repack(const float* __restrict__ W,
                                                unsigned short* __restrict__ out,
                                                int M, int ktlog2, int total){
  int idx = blockIdx.x*256 + threadIdx.x;
  if(idx >= total) return;
  int j    = idx & 7;
  int lane = (idx>>3) & 63;
  int kt   = (idx>>9) & ((1<<ktlog2)-1);
  int mt   = idx >> (9+ktlog2);
  int k = kt*32 + (lane>>4)*8 + j;
  int m = mt*16 + (lane&15);
  out[idx] = f2b(W[k*M + m]);
}

// same, but hi/lo split (3-term bf16 decomposition)
__global__ __launch_bounds__(256) void k_repack2(const float* __restrict__ W,
                                                 unsigned short* __restrict__ oh,
                                                 unsigned short* __restrict__ ol,
                                                 int M, int ktlog2, int total){
  int idx = blockIdx.x*256 + threadIdx.x;
  if(idx >= total) return;
  int j    = idx & 7;
  int lane = (idx>>3) & 63;
  int kt   = (idx>>9) & ((1<<ktlog2)-1);
  int mt   = idx >> (9+ktlog2);
  int k = kt*32 + (lane>>4)*8 + j;
  int m = mt*16 + (lane&15);
  float v = W[k*M + m];
  unsigned short h = f2b(v);
  oh[idx] = h;
  ol[idx] = f2b(v - b2f(h));
}

// ---------------- K1: xn = LN(x, n2)  (512 rows x 512), fp32 -> bf16 hi/lo ----------------
__global__ __launch_bounds__(256) void k1_ln(const float* __restrict__ x,
                                             const float* __restrict__ s,
                                             const float* __restrict__ b,
                                             unsigned short* __restrict__ oh,
                                             unsigned short* __restrict__ ol){
  int row = blockIdx.x, t = threadIdx.x;
  const float* xr = x + row*512;
  float v0 = xr[t], v1 = xr[t+256];
  float sum = v0+v1, sq = v0*v0+v1*v1;
  for(int o=32;o>=1;o>>=1){ sum += __shfl_down(sum,o); sq += __shfl_down(sq,o); }
  __shared__ float ls[4], lq[4];
  int w = t>>6;
  if((t&63)==0){ ls[w]=sum; lq[w]=sq; }
  __syncthreads();
  sum = ls[0]+ls[1]+ls[2]+ls[3]; sq = lq[0]+lq[1]+lq[2]+lq[3];
  float m = sum*(1.f/512.f);
  float rstd = rsqrtf(sq*(1.f/512.f) - m*m + 1e-5f);
  float a0 = (v0-m)*rstd*s[t]     + b[t];
  float a1 = (v1-m)*rstd*s[t+256] + b[t+256];
  unsigned short h0 = f2b(a0), h1 = f2b(a1);
  oh[row*512+t]     = h0;  ol[row*512+t]     = f2b(a0 - b2f(h0));
  oh[row*512+t+256] = h1;  ol[row*512+t+256] = f2b(a1 - b2f(h1));
}

// ---------------- K2: h1 = gelu(xn @ nffn1_W + b1)  split-precision ----------------
__global__ __launch_bounds__(256) void k2_ffn1(const unsigned short* __restrict__ xh,
                                               const unsigned short* __restrict__ xl,
                                               const unsigned short* __restrict__ Wh,
                                               const unsigned short* __restrict__ Wl,
                                               const float* __restrict__ b1,
                                               unsigned short* __restrict__ hh,
                                               unsigned short* __restrict__ hl){
  int t = threadIdx.x, w = t>>6, lane = t&63, l15 = lane&15, q = lane>>4;
  int rowbase = blockIdx.y*64;
  f32x4 acc[2][4];
  for(int a=0;a<2;a++) for(int n=0;n<4;n++) acc[a][n] = (f32x4){0.f,0.f,0.f,0.f};
  for(int kt=0;kt<16;kt++){
    s16x8 bh[4], bl[4];
    for(int nt=0;nt<4;nt++){
      int off = (rowbase + nt*16 + l15)*512 + kt*32 + q*8;
      bh[nt] = *(const s16x8*)(xh + off);
      bl[nt] = *(const s16x8*)(xl + off);
    }
    for(int mtl=0;mtl<2;mtl++){
      int mtg = blockIdx.x*8 + w*2 + mtl;
      int wi = ((mtg*16 + kt)*64 + lane)*8;
      s16x8 ah = *(const s16x8*)(Wh + wi);
      s16x8 al = *(const s16x8*)(Wl + wi);
      for(int nt=0;nt<4;nt++){
        acc[mtl][nt] = MFMA(ah, bh[nt], acc[mtl][nt]);
        acc[mtl][nt] = MFMA(ah, bl[nt], acc[mtl][nt]);
        acc[mtl][nt] = MFMA(al, bh[nt], acc[mtl][nt]);
      }
    }
  }
  for(int mtl=0;mtl<2;mtl++){
    int mtg = blockIdx.x*8 + w*2 + mtl;
    int col0 = mtg*16 + q*4;
    f32x4 bb = *(const f32x4*)(b1 + col0);
    for(int nt=0;nt<4;nt++){
      int row = rowbase + nt*16 + l15;
      us4 vh, vl;
      for(int r=0;r<4;r++){
        float g = geluf(acc[mtl][nt][r] + bb[r]);
        unsigned short h = f2b(g);
        vh[r] = h; vl[r] = f2b(g - b2f(h));
      }
      *(us4*)(hh + row*2048 + col0) = vh;
      *(us4*)(hl + row*2048 + col0) = vl;
    }
  }
}

// ---------------- K3: x_out = x + h1 @ nffn2_W + b2  split-precision, fp32 out ----------------
__global__ __launch_bounds__(256) void k3_ffn2(const unsigned short* __restrict__ hh,
                                               const unsigned short* __restrict__ hl,
                                               const unsigned short* __restrict__ Wh,
                                               const unsigned short* __restrict__ Wl,
                                               const float* __restrict__ b2,
                                               const float* __restrict__ x,
                                               float* __restrict__ xout){
  int t = threadIdx.x, w = t>>6, lane = t&63, l15 = lane&15, q = lane>>4;
  int row = blockIdx.y*64 + w*16 + l15;
  f32x4 acc[2]; acc[0] = (f32x4){0.f,0.f,0.f,0.f}; acc[1] = acc[0];
  for(int kt=0;kt<64;kt++){
    int off = row*2048 + kt*32 + q*8;
    s16x8 bh = *(const s16x8*)(hh + off);
    s16x8 bl = *(const s16x8*)(hl + off);
    for(int mtl=0;mtl<2;mtl++){
      int mtg = blockIdx.x*2 + mtl;
      int wi = ((mtg*64 + kt)*64 + lane)*8;
      s16x8 ah = *(const s16x8*)(Wh + wi);
      s16x8 al = *(const s16x8*)(Wl + wi);
      acc[mtl] = MFMA(ah, bh, acc[mtl]);
      acc[mtl] = MFMA(ah, bl, acc[mtl]);
      acc[mtl] = MFMA(al, bh, acc[mtl]);
    }
  }
  for(int mtl=0;mtl<2;mtl++){
    int col0 = (blockIdx.x*2 + mtl)*16 + q*4;
    f32x4 xv = *(const f32x4*)(x + row*512 + col0);
    f32x4 bb = *(const f32x4*)(b2 + col0);
    f32x4 ov;
    for(int r=0;r<4;r++) ov[r] = xv[r] + acc[mtl][r] + bb[r];
    *(f32x4*)(xout + row*512 + col0) = ov;
  }
}

// ---------------- K4: o = LN(x_out,en1) @ o12_W + o12_b -> o1,o2 (all fp32) ----------------
__global__ __launch_bounds__(256) void k4_o12(const float* __restrict__ xout,
                                              const float* __restrict__ s,
                                              const float* __restrict__ b,
                                              const float* __restrict__ o12W,
                                              const float* __restrict__ o12b,
                                              float* __restrict__ o1, float* __restrict__ o2){
  int row = blockIdx.x, t = threadIdx.x;
  const float* xr = xout + row*512;
  float v0 = xr[t], v1 = xr[t+256];
  float sum = v0+v1, sq = v0*v0+v1*v1;
  for(int o=32;o>=1;o>>=1){ sum += __shfl_down(sum,o); sq += __shfl_down(sq,o); }
  __shared__ float ls[4], lq[4];
  __shared__ float red[4][8];
  int w = t>>6;
  if((t&63)==0){ ls[w]=sum; lq[w]=sq; }
  __syncthreads();
  sum = ls[0]+ls[1]+ls[2]+ls[3]; sq = lq[0]+lq[1]+lq[2]+lq[3];
  float m = sum*(1.f/512.f);
  float rstd = rsqrtf(sq*(1.f/512.f) - m*m + 1e-5f);
  float x0 = (v0-m)*rstd*s[t]     + b[t];
  float x1 = (v1-m)*rstd*s[t+256] + b[t+256];
  f32x4 w0a = *(const f32x4*)(o12W + t*8),       w0b = *(const f32x4*)(o12W + t*8 + 4);
  f32x4 w1a = *(const f32x4*)(o12W + (t+256)*8), w1b = *(const f32x4*)(o12W + (t+256)*8 + 4);
  float pa[8];
  for(int r=0;r<4;r++){ pa[r]   = x0*w0a[r] + x1*w1a[r];
                        pa[4+r] = x0*w0b[r] + x1*w1b[r]; }
  for(int o=32;o>=1;o>>=1) for(int k=0;k<8;k++) pa[k] += __shfl_down(pa[k],o);
  if((t&63)==0) for(int k=0;k<8;k++) red[w][k] = pa[k];
  __syncthreads();
  if(t<8){
    float tot = red[0][t]+red[1][t]+red[2][t]+red[3][t] + o12b[t];
    if(t<4) o1[row*4+t] = tot; else o2[row*4+(t-4)] = tot;
  }
}

// ---------------- K5: p1 = p + outer(o1[i],o2[j]) @ o3_W + o3_b  (all fp32) ----------------
__global__ __launch_bounds__(256) void k5_p1(const float* __restrict__ p,
                                             const float* __restrict__ o3W,
                                             const float* __restrict__ o3b,
                                             const float* __restrict__ o1,
                                             const float* __restrict__ o2,
                                             float* __restrict__ p1){
  __shared__ float w_s[2048];
  __shared__ float b_s[128];
  int t = threadIdx.x;
  for(int r=0;r<8;r++) w_s[t*8+r] = o3W[t*8+r];
  if(t<128) b_s[t] = o3b[t];
  __syncthreads();
  int g = blockIdx.x*16 + (t>>4);
  int e0 = (t&15)*8;
  int bb = g>>16, ii = (g>>8)&255, jj = g&255;
  const float* o1p = o1 + (bb*256+ii)*4;
  const float* o2p = o2 + (bb*256+jj)*4;
  float c[16];
  for(int h=0;h<4;h++) for(int g2=0;g2<4;g2++) c[h*4+g2] = o1p[h]*o2p[g2];
  f32x4 pv0 = *(const f32x4*)(p + (long)g*128 + e0);
  f32x4 pv1 = *(const f32x4*)(p + (long)g*128 + e0 + 4);
  float acc[8];
  for(int r=0;r<4;r++){ acc[r] = pv0[r] + b_s[e0+r]; acc[4+r] = pv1[r] + b_s[e0+4+r]; }
  for(int m=0;m<16;m++){
    const float* wr = &w_s[m*128 + e0];
    for(int r=0;r<8;r++) acc[r] += c[m]*wr[r];
  }
  f32x4 s0, s1;
  for(int r=0;r<4;r++){ s0[r] = acc[r]; s1[r] = acc[4+r]; }
  *(f32x4*)(p1 + (long)g*128 + e0)     = s0;
  *(f32x4*)(p1 + (long)g*128 + e0 + 4) = s1;
}

// ---------------- LN stage: 64 rows of 128 (fp32 src) -> bf16 LDS tile(s), stride 136 ----------------
DI void ln_stage64(const float* __restrict__ psrc,
                   const float* __restrict__ s2,
                   const float* __restrict__ b2,
                   unsigned short* pnh, unsigned short* pnl, int t){
  int lr = t>>2, qt = t&3, e0 = qt*32;
  const float* pr = psrc + lr*128 + e0;
  float v[32];
  for(int c=0;c<8;c++){ f32x4 u = *(const f32x4*)(pr + c*4); for(int r=0;r<4;r++) v[c*4+r] = u[r]; }
  float s = 0.f, sq = 0.f;
  for(int k=0;k<32;k++){ s += v[k]; sq += v[k]*v[k]; }
  s  += __shfl_xor(s,1);  s  += __shfl_xor(s,2);
  sq += __shfl_xor(sq,1); sq += __shfl_xor(sq,2);
  float m = s*(1.f/128.f);
  float rstd = rsqrtf(sq*(1.f/128.f) - m*m + 1e-5f);
  for(int c=0;c<8;c++){
    f32x4 sv = *(const f32x4*)(s2 + e0 + c*4), bv = *(const f32x4*)(b2 + e0 + c*4);
    us4 vh, vl;
    for(int r=0;r<4;r++){
      float val = (v[c*4+r]-m)*rstd*sv[r] + bv[r];
      unsigned short h = f2b(val);
      vh[r] = h; vl[r] = f2b(val - b2f(h));
    }
    *(us4*)&pnh[lr*136 + e0 + c*4] = vh;
    if(pnl) *(us4*)&pnl[lr*136 + e0 + c*4] = vl;
  }
}

// ---------------- K7a: tt = LN(p1,en2)@t_W + t_b ; accumulate a, bsum ----------------
__global__ __launch_bounds__(256) void k7a_tt(const float* __restrict__ p1,
                                              const float* __restrict__ en2s,
                                              const float* __restrict__ en2b,
                                              const unsigned short* __restrict__ tWT,
                                              const float* __restrict__ tb,
                                              const int* __restrict__ am,
                                              float* __restrict__ a_acc,
                                              float* __restrict__ bs_acc){
  __shared__ __align__(16) unsigned short pn[64*136];
  int t = threadIdx.x;
  long gbase = (long)blockIdx.x*64;
  ln_stage64(p1 + gbase*128, en2s, en2b, pn, (unsigned short*)0, t);
  __syncthreads();
  int w = t>>6, lane = t&63, l15 = lane&15, q = lane>>4;
  f32x4 acc = (f32x4){0.f,0.f,0.f,0.f};
  for(int kt=0;kt<4;kt++){
    s16x8 bf = *(const s16x8*)&pn[(w*16+l15)*136 + kt*32 + q*8];
    s16x8 af = *(const s16x8*)(tWT + (kt*64 + lane)*8);
    acc = MFMA(af, bf, acc);
  }
  f32x4 tb4 = *(const f32x4*)(tb + q*4);
  for(int r=0;r<4;r++) acc[r] += tb4[r];
  long g = gbase + w*16 + l15;
  int bb = (int)(g>>16), ii = ((int)g>>8)&255, jj = (int)g&255;
  int msk = am[(bb*256+ii)*256 + jj];
  float pr4[4];
  for(int r=0;r<4;r++) pr4[r] = __shfl_xor(acc[r], 16);
  if(msk){
    if(q==0){      for(int r=0;r<4;r++) atomicAdd(&a_acc[(bb*256+jj)*4+r],  sigmf(acc[r]*pr4[r])); }
    else if(q==2){ for(int r=0;r<4;r++) atomicAdd(&bs_acc[(bb*256+ii)*4+r], sigmf(acc[r]*pr4[r])); }
  }
}

// ---------------- K6b: A2 = a@t6_W ; Bs2 = bsum@t6_W + t6_b ----------------
__global__ __launch_bounds__(128) void k6b(const float* __restrict__ a_acc,
                                           const float* __restrict__ bs_acc,
                                           const float* __restrict__ t6W,
                                           const float* __restrict__ t6b,
                                           float* __restrict__ A2, float* __restrict__ Bs2){
  int d = blockIdx.x, e = threadIdx.x;
  float sa = 0.f, sb = 0.f;
  for(int h=0;h<4;h++){
    float wv = t6W[h*128+e];
    sa += a_acc[d*4+h]*wv;
    sb += bs_acc[d*4+h]*wv;
  }
  A2[d*128+e]  = sa;
  Bs2[d*128+e] = sb + t6b[e];
}

// ---------------- K7b: t5 = LN(p1,en2)@t5_W + t5_b (split) ; p2 = p1 + sigmoid(...) ----------------
__global__ __launch_bounds__(256) void k7b_p2(float* __restrict__ dp,
                                              const float* __restrict__ en2s,
                                              const float* __restrict__ en2b,
                                              const unsigned short* __restrict__ t5Wh,
                                              const unsigned short* __restrict__ t5Wl,
                                              const float* __restrict__ t5b,
                                              const float* __restrict__ A2,
                                              const float* __restrict__ Bs2,
                                              const int* __restrict__ am){
  __shared__ __align__(16) unsigned short pnh[64*136];
  __shared__ __align__(16) unsigned short pnl[64*136];
  int t = threadIdx.x;
  long gbase = (long)blockIdx.x*64;
  ln_stage64(dp + gbase*128, en2s, en2b, pnh, pnl, t);
  __syncthreads();
  int w = t>>6, lane = t&63, l15 = lane&15, q = lane>>4;
  for(int mtl=0;mtl<2;mtl++){
    int mtg = w*2 + mtl;
    s16x8 afh[4], afl[4];
    for(int kt=0;kt<4;kt++){
      int wi = ((mtg*4+kt)*64 + lane)*8;
      afh[kt] = *(const s16x8*)(t5Wh + wi);
      afl[kt] = *(const s16x8*)(t5Wl + wi);
    }
    int e0 = mtg*16 + q*4;
    f32x4 t5b4 = *(const f32x4*)(t5b + e0);
    for(int nt=0;nt<4;nt++){
      f32x4 acc = (f32x4){0.f,0.f,0.f,0.f};
      for(int kt=0;kt<4;kt++){
        s16x8 bh = *(const s16x8*)&pnh[(nt*16+l15)*136 + kt*32 + q*8];
        s16x8 bl = *(const s16x8*)&pnl[(nt*16+l15)*136 + kt*32 + q*8];
        acc = MFMA(afh[kt], bh, acc);
        acc = MFMA(afh[kt], bl, acc);
        acc = MFMA(afl[kt], bh, acc);
      }
      long g = gbase + nt*16 + l15;
      int bb = (int)(g>>16), ii = ((int)g>>8)&255, jj = (int)g&255;
      int msk = am[(bb*256+ii)*256 + jj];
      const float* A2p = A2 + (bb*256+jj)*128 + e0;
      const float* Bsp = Bs2 + (bb*256+ii)*128 + e0;
      f32x4 p1v = *(const f32x4*)(dp + g*128 + e0);
      f32x4 ov;
      for(int r=0;r<4;r++){
        float sg = 0.f;
        if(msk){
          float t56 = (acc[r] + t5b4[r]) * (A2p[r] + Bsp[r]);
          sg = sigmf(t56);
        }
        ov[r] = p1v[r] + sg;
      }
      *(f32x4*)(dp + g*128 + e0) = ov;
    }
  }
}

// ---------------- K8: p3 = p2 + gelu(LN(p2,en3)@effn1+b)@effn2 + b  (p fp32) ----------------
__global__ __launch_bounds__(256) void k8_effn(float* __restrict__ dp,
                                               const float* __restrict__ en3s,
                                               const float* __restrict__ en3b,
                                               const unsigned short* __restrict__ W1T,
                                               const float* __restrict__ b1,
                                               const unsigned short* __restrict__ W2T,
                                               const float* __restrict__ b2){
  __shared__ __align__(16) unsigned short pn3[32*136];
  __shared__ __align__(16) unsigned short hT[32*520];
  int t = threadIdx.x;
  long base = (long)blockIdx.x*32;
  { // phase A: LN(p2, en3) -> pn3 tile
    int lr = t>>3, oct = t&7, e0 = oct*16;
    const float* pr = dp + (base+lr)*128 + e0;
    float v[16];
    for(int c=0;c<4;c++){ f32x4 u = *(const f32x4*)(pr + c*4); for(int r=0;r<4;r++) v[c*4+r] = u[r]; }
    float s = 0.f, sq = 0.f;
    for(int k=0;k<16;k++){ s += v[k]; sq += v[k]*v[k]; }
    s  += __shfl_xor(s,1);  s  += __shfl_xor(s,2);  s  += __shfl_xor(s,4);
    sq += __shfl_xor(sq,1); sq += __shfl_xor(sq,2); sq += __shfl_xor(sq,4);
    float m = s*(1.f/128.f);
    float rstd = rsqrtf(sq*(1.f/128.f) - m*m + 1e-5f);
    for(int c=0;c<4;c++){
      f32x4 sv = *(const f32x4*)(en3s + e0 + c*4), bv = *(const f32x4*)(en3b + e0 + c*4);
      us4 ov;
      for(int r=0;r<4;r++) ov[r] = f2b((v[c*4+r]-m)*rstd*sv[r] + bv[r]);
      *(us4*)&pn3[lr*136 + e0 + c*4] = ov;
    }
  }
  __syncthreads();
  int w = t>>6, lane = t&63, l15 = lane&15, q = lane>>4;
  { // GEMM1: hT = gelu(W1T * pn3^T + b1)
    s16x8 bfr[2][4];
    for(int nt=0;nt<2;nt++) for(int kt=0;kt<4;kt++)
      bfr[nt][kt] = *(const s16x8*)&pn3[(nt*16+l15)*136 + kt*32 + q*8];
    for(int mtl=0;mtl<8;mtl++){
      int mtg = w*8 + mtl;
      s16x8 af[4];
      for(int kt=0;kt<4;kt++) af[kt] = *(const s16x8*)(W1T + ((mtg*4+kt)*64 + lane)*8);
      int col0 = mtg*16 + q*4;
      f32x4 bb = *(const f32x4*)(b1 + col0);
      for(int nt=0;nt<2;nt++){
        f32x4 acc = (f32x4){0.f,0.f,0.f,0.f};
        for(int kt=0;kt<4;kt++) acc = MFMA(af[kt], bfr[nt][kt], acc);
        us4 hv;
        for(int r=0;r<4;r++) hv[r] = f2b(geluf(acc[r] + bb[r]));
        *(us4*)&hT[(nt*16+l15)*520 + col0] = hv;
      }
    }
  }
  __syncthreads();
  { // GEMM2: out = p2 + W2T * hT^T + b2
    f32x4 acc2[2][2];
    for(int a=0;a<2;a++) for(int n=0;n<2;n++) acc2[a][n] = (f32x4){0.f,0.f,0.f,0.f};
    for(int kt=0;kt<16;kt++){
      s16x8 bfr[2];
      for(int nt=0;nt<2;nt++) bfr[nt] = *(const s16x8*)&hT[(nt*16+l15)*520 + kt*32 + q*8];
      for(int mtl=0;mtl<2;mtl++){
        int m2 = w*2 + mtl;
        s16x8 af = *(const s16x8*)(W2T + ((m2*16+kt)*64 + lane)*8);
        for(int nt=0;nt<2;nt++) acc2[mtl][nt] = MFMA(af, bfr[nt], acc2[mtl][nt]);
      }
    }
    for(int mtl=0;mtl<2;mtl++){
      int m2 = w*2 + mtl;
      int col0 = m2*16 + q*4;
      f32x4 bb = *(const f32x4*)(b2 + col0);
      for(int nt=0;nt<2;nt++){
        long g = base + nt*16 + l15;
        f32x4 p2v = *(const f32x4*)(dp + g*128 + col0);
        f32x4 ov;
        for(int r=0;r<4;r++) ov[r] = p2v[r] + acc2[mtl][nt][r] + bb[r];
        *(f32x4*)(dp + g*128 + col0) = ov;
      }
    }
  }
}

extern "C" void kernel_launch(void* const* d_in, const int* in_sizes, int n_in,
                              void* d_out, int out_size, void* d_ws, size_t ws_size,
                              hipStream_t stream) {
  const float* x      = (const float*)d_in[0];
  const float* p      = (const float*)d_in[1];
  const int*   am     = (const int*)d_in[2];
  const float* nffn1W = (const float*)d_in[7];
  const float* nffn1b = (const float*)d_in[8];
  const float* nffn2W = (const float*)d_in[9];
  const float* nffn2b = (const float*)d_in[10];
  const float* o12W   = (const float*)d_in[11];
  const float* o12b   = (const float*)d_in[12];
  const float* o3W    = (const float*)d_in[13];
  const float* o3b    = (const float*)d_in[14];
  const float* tW     = (const float*)d_in[15];
  const float* tb     = (const float*)d_in[16];
  const float* t5W    = (const float*)d_in[17];
  const float* t5b    = (const float*)d_in[18];
  const float* t6W    = (const float*)d_in[19];
  const float* t6b    = (const float*)d_in[20];
  const float* e1W    = (const float*)d_in[21];
  const float* e1b    = (const float*)d_in[22];
  const float* e2W    = (const float*)d_in[23];
  const float* e2b    = (const float*)d_in[24];
  const float* n2s    = (const float*)d_in[27];
  const float* n2b    = (const float*)d_in[28];
  const float* en1s   = (const float*)d_in[29];
  const float* en1b   = (const float*)d_in[30];
  const float* en2s   = (const float*)d_in[31];
  const float* en2b   = (const float*)d_in[32];
  const float* en3s   = (const float*)d_in[33];
  const float* en3b   = (const float*)d_in[34];

  float* ox  = (float*)d_out;            // x out: 262144 f32
  float* opx = (float*)d_out + 262144;   // p out: 8388608 f32

  char* ws = (char*)d_ws;
  float* a_acc  = (float*)(ws + 0);        // 2048 f32
  float* bs_acc = (float*)(ws + 8192);     // 2048 f32
  float* o1w    = (float*)(ws + 16384);    // 2048 f32
  float* o2w    = (float*)(ws + 24576);    // 2048 f32
  float* A2     = (float*)(ws + 32768);    // 65536 f32
  float* Bs2    = (float*)(ws + 294912);   // 65536 f32
  unsigned short* xnh = (unsigned short*)(ws + 557056);    // 262144 bf16
  unsigned short* xnl = (unsigned short*)(ws + 1081344);   // 262144 bf16
  unsigned short* h1h = (unsigned short*)(ws + 1605632);   // 1048576 bf16
  unsigned short* h1l = (unsigned short*)(ws + 3702784);   // 1048576 bf16
  unsigned short* tWT  = (unsigned short*)(ws + 5799936);  // 2048 bf16
  unsigned short* t5Wh = (unsigned short*)(ws + 5804032);  // 16384 bf16
  unsigned short* t5Wl = (unsigned short*)(ws + 5836800);  // 16384 bf16
  unsigned short* W1T  = (unsigned short*)(ws + 5869568);  // 65536 bf16 (effn1)
  unsigned short* W2T  = (unsigned short*)(ws + 6000640);  // 65536 bf16 (effn2)
  unsigned short* n1h  = (unsigned short*)(ws + 6131712);  // 1048576 bf16
  unsigned short* n1l  = (unsigned short*)(ws + 8228864);  // 1048576 bf16
  unsigned short* n2h  = (unsigned short*)(ws + 10326016); // 1048576 bf16
  unsigned short* n2l  = (unsigned short*)(ws + 12423168); // 1048576 bf16

  hipMemsetAsync(ws, 0, 16384, stream);

  k_repack <<<2048/256,    256, 0, stream>>>(tW,  tWT,  16,  2, 2048);
  k_repack2<<<16384/256,   256, 0, stream>>>(t5W, t5Wh, t5Wl, 128, 2, 16384);
  k_repack <<<65536/256,   256, 0, stream>>>(e1W, W1T,  512, 2, 65536);
  k_repack <<<65536/256,   256, 0, stream>>>(e2W, W2T,  128, 4, 65536);
  k_repack2<<<1048576/256, 256, 0, stream>>>(nffn1W, n1h, n1l, 2048, 4, 1048576);
  k_repack2<<<1048576/256, 256, 0, stream>>>(nffn2W, n2h, n2l, 512,  6, 1048576);

  k1_ln<<<512, 256, 0, stream>>>(x, n2s, n2b, xnh, xnl);
  k2_ffn1<<<dim3(16,8), 256, 0, stream>>>(xnh, xnl, n1h, n1l, nffn1b, h1h, h1l);
  k3_ffn2<<<dim3(16,8), 256, 0, stream>>>(h1h, h1l, n2h, n2l, nffn2b, x, ox);
  k4_o12<<<512, 256, 0, stream>>>(ox, en1s, en1b, o12W, o12b, o1w, o2w);

  k5_p1<<<8192, 256, 0, stream>>>(p, o3W, o3b, o1w, o2w, opx);
  k7a_tt<<<2048, 256, 0, stream>>>(opx, en2s, en2b, tWT, tb, am, a_acc, bs_acc);
  k6b<<<512, 128, 0, stream>>>(a_acc, bs_acc, t6W, t6b, A2, Bs2);
  k7b_p2<<<2048, 256, 0, stream>>>(opx, en2s, en2b, t5Wh, t5Wl, t5b, A2, Bs2, am);
  k8_effn<<<4096, 256, 0, stream>>>(opx, en3s, en3b, W1T, e1b, W2T, e2b);
}

// Round 4
// 495.514 us; speedup vs baseline: 1.1803x; 1.1803x over previous
//
#include <hip/hip_runtime.h>
#include <hip/hip_bf16.h>

typedef __attribute__((ext_vector_type(8))) short s16x8;
typedef __attribute__((ext_vector_type(4))) float f32x4;
typedef __attribute__((ext_vector_type(4))) unsigned short us4;

#define DI __device__ __forceinline__

DI float b2f(unsigned short u){ union{float f; unsigned int i;} v; v.i = ((unsigned int)u)<<16; return v.f; }
DI unsigned short f2b(float f){ union{float f; unsigned int i;} v; v.f = f; unsigned int r = v.i + 0x7FFF + ((v.i>>16)&1u); return (unsigned short)(r>>16); }
DI float geluf(float x){ return 0.5f*x*(1.f + erff(x*0.70710678118654752f)); }
DI float sigmf(float x){ return 1.f/(1.f + expf(-x)); }

#define MFMA(a,b,c) __builtin_amdgcn_mfma_f32_16x16x32_bf16((a),(b),(c),0,0,0)

// ---------------- repack W (K x M, row-major fp32) into bf16 MFMA A-frag layout ----------------
// one thread -> 8 contiguous outputs; lanes are m-contiguous (coalesced reads & writes)
__global__ __launch_bounds__(256) void k_repack(const float* __restrict__ W,
                                                unsigned short* __restrict__ out,
                                                int M, int ktlog2, int nthreads){
  int idx = blockIdx.x*256 + threadIdx.x;
  if(idx >= nthreads) return;
  int lane = idx & 63;
  int kt   = (idx>>6) & ((1<<ktlog2)-1);
  int mt   = idx >> (6+ktlog2);
  int k0 = kt*32 + (lane>>4)*8;
  int m  = mt*16 + (lane&15);
  s16x8 o;
  for(int j=0;j<8;j++) o[j] = (short)f2b(W[(k0+j)*M + m]);
  *(s16x8*)(out + (long)idx*8) = o;
}

// same, hi/lo split (3-term bf16 decomposition)
__global__ __launch_bounds__(256) void k_repack2(const float* __restrict__ W,
                                                 unsigned short* __restrict__ oh,
                                                 unsigned short* __restrict__ ol,
                                                 int M, int ktlog2, int nthreads){
  int idx = blockIdx.x*256 + threadIdx.x;
  if(idx >= nthreads) return;
  int lane = idx & 63;
  int kt   = (idx>>6) & ((1<<ktlog2)-1);
  int mt   = idx >> (6+ktlog2);
  int k0 = kt*32 + (lane>>4)*8;
  int m  = mt*16 + (lane&15);
  s16x8 vh, vl;
  for(int j=0;j<8;j++){
    float v = W[(k0+j)*M + m];
    unsigned short h = f2b(v);
    vh[j] = (short)h;
    vl[j] = (short)f2b(v - b2f(h));
  }
  *(s16x8*)(oh + (long)idx*8) = vh;
  *(s16x8*)(ol + (long)idx*8) = vl;
}

// ---------------- K1: xn = LN(x, n2)  (512 rows x 512), fp32 -> bf16 hi/lo ----------------
__global__ __launch_bounds__(256) void k1_ln(const float* __restrict__ x,
                                             const float* __restrict__ s,
                                             const float* __restrict__ b,
                                             unsigned short* __restrict__ oh,
                                             unsigned short* __restrict__ ol){
  int row = blockIdx.x, t = threadIdx.x;
  const float* xr = x + row*512;
  float v0 = xr[t], v1 = xr[t+256];
  float sum = v0+v1, sq = v0*v0+v1*v1;
  for(int o=32;o>=1;o>>=1){ sum += __shfl_down(sum,o); sq += __shfl_down(sq,o); }
  __shared__ float ls[4], lq[4];
  int w = t>>6;
  if((t&63)==0){ ls[w]=sum; lq[w]=sq; }
  __syncthreads();
  sum = ls[0]+ls[1]+ls[2]+ls[3]; sq = lq[0]+lq[1]+lq[2]+lq[3];
  float m = sum*(1.f/512.f);
  float rstd = rsqrtf(sq*(1.f/512.f) - m*m + 1e-5f);
  float a0 = (v0-m)*rstd*s[t]     + b[t];
  float a1 = (v1-m)*rstd*s[t+256] + b[t+256];
  unsigned short h0 = f2b(a0), h1 = f2b(a1);
  oh[row*512+t]     = h0;  ol[row*512+t]     = f2b(a0 - b2f(h0));
  oh[row*512+t+256] = h1;  ol[row*512+t+256] = f2b(a1 - b2f(h1));
}

// ---------------- K2: h1 = gelu(xn @ nffn1_W + b1)  split-precision ----------------
__global__ __launch_bounds__(256) void k2_ffn1(const unsigned short* __restrict__ xh,
                                               const unsigned short* __restrict__ xl,
                                               const unsigned short* __restrict__ Wh,
                                               const unsigned short* __restrict__ Wl,
                                               const float* __restrict__ b1,
                                               unsigned short* __restrict__ hh,
                                               unsigned short* __restrict__ hl){
  int t = threadIdx.x, w = t>>6, lane = t&63, l15 = lane&15, q = lane>>4;
  int rowbase = blockIdx.y*64;
  f32x4 acc[2][4];
  for(int a=0;a<2;a++) for(int n=0;n<4;n++) acc[a][n] = (f32x4){0.f,0.f,0.f,0.f};
  for(int kt=0;kt<16;kt++){
    s16x8 bh[4], bl[4];
    for(int nt=0;nt<4;nt++){
      int off = (rowbase + nt*16 + l15)*512 + kt*32 + q*8;
      bh[nt] = *(const s16x8*)(xh + off);
      bl[nt] = *(const s16x8*)(xl + off);
    }
    for(int mtl=0;mtl<2;mtl++){
      int mtg = blockIdx.x*8 + w*2 + mtl;
      int wi = ((mtg*16 + kt)*64 + lane)*8;
      s16x8 ah = *(const s16x8*)(Wh + wi);
      s16x8 al = *(const s16x8*)(Wl + wi);
      for(int nt=0;nt<4;nt++){
        acc[mtl][nt] = MFMA(ah, bh[nt], acc[mtl][nt]);
        acc[mtl][nt] = MFMA(ah, bl[nt], acc[mtl][nt]);
        acc[mtl][nt] = MFMA(al, bh[nt], acc[mtl][nt]);
      }
    }
  }
  for(int mtl=0;mtl<2;mtl++){
    int mtg = blockIdx.x*8 + w*2 + mtl;
    int col0 = mtg*16 + q*4;
    f32x4 bb = *(const f32x4*)(b1 + col0);
    for(int nt=0;nt<4;nt++){
      int row = rowbase + nt*16 + l15;
      us4 vh, vl;
      for(int r=0;r<4;r++){
        float g = geluf(acc[mtl][nt][r] + bb[r]);
        unsigned short h = f2b(g);
        vh[r] = h; vl[r] = f2b(g - b2f(h));
      }
      *(us4*)(hh + row*2048 + col0) = vh;
      *(us4*)(hl + row*2048 + col0) = vl;
    }
  }
}

// ---------------- K3: x_out = x + h1 @ nffn2_W + b2  split-precision, fp32 out ----------------
__global__ __launch_bounds__(256) void k3_ffn2(const unsigned short* __restrict__ hh,
                                               const unsigned short* __restrict__ hl,
                                               const unsigned short* __restrict__ Wh,
                                               const unsigned short* __restrict__ Wl,
                                               const float* __restrict__ b2,
                                               const float* __restrict__ x,
                                               float* __restrict__ xout){
  int t = threadIdx.x, w = t>>6, lane = t&63, l15 = lane&15, q = lane>>4;
  int row = blockIdx.y*64 + w*16 + l15;
  f32x4 acc[2]; acc[0] = (f32x4){0.f,0.f,0.f,0.f}; acc[1] = acc[0];
  for(int kt=0;kt<64;kt++){
    int off = row*2048 + kt*32 + q*8;
    s16x8 bh = *(const s16x8*)(hh + off);
    s16x8 bl = *(const s16x8*)(hl + off);
    for(int mtl=0;mtl<2;mtl++){
      int mtg = blockIdx.x*2 + mtl;
      int wi = ((mtg*64 + kt)*64 + lane)*8;
      s16x8 ah = *(const s16x8*)(Wh + wi);
      s16x8 al = *(const s16x8*)(Wl + wi);
      acc[mtl] = MFMA(ah, bh, acc[mtl]);
      acc[mtl] = MFMA(ah, bl, acc[mtl]);
      acc[mtl] = MFMA(al, bh, acc[mtl]);
    }
  }
  for(int mtl=0;mtl<2;mtl++){
    int col0 = (blockIdx.x*2 + mtl)*16 + q*4;
    f32x4 xv = *(const f32x4*)(x + row*512 + col0);
    f32x4 bb = *(const f32x4*)(b2 + col0);
    f32x4 ov;
    for(int r=0;r<4;r++) ov[r] = xv[r] + acc[mtl][r] + bb[r];
    *(f32x4*)(xout + row*512 + col0) = ov;
  }
}

// ---------------- K4: o = LN(x_out,en1) @ o12_W + o12_b -> o1,o2 (all fp32) ----------------
__global__ __launch_bounds__(256) void k4_o12(const float* __restrict__ xout,
                                              const float* __restrict__ s,
                                              const float* __restrict__ b,
                                              const float* __restrict__ o12W,
                                              const float* __restrict__ o12b,
                                              float* __restrict__ o1, float* __restrict__ o2){
  int row = blockIdx.x, t = threadIdx.x;
  const float* xr = xout + row*512;
  float v0 = xr[t], v1 = xr[t+256];
  float sum = v0+v1, sq = v0*v0+v1*v1;
  for(int o=32;o>=1;o>>=1){ sum += __shfl_down(sum,o); sq += __shfl_down(sq,o); }
  __shared__ float ls[4], lq[4];
  __shared__ float red[4][8];
  int w = t>>6;
  if((t&63)==0){ ls[w]=sum; lq[w]=sq; }
  __syncthreads();
  sum = ls[0]+ls[1]+ls[2]+ls[3]; sq = lq[0]+lq[1]+lq[2]+lq[3];
  float m = sum*(1.f/512.f);
  float rstd = rsqrtf(sq*(1.f/512.f) - m*m + 1e-5f);
  float x0 = (v0-m)*rstd*s[t]     + b[t];
  float x1 = (v1-m)*rstd*s[t+256] + b[t+256];
  f32x4 w0a = *(const f32x4*)(o12W + t*8),       w0b = *(const f32x4*)(o12W + t*8 + 4);
  f32x4 w1a = *(const f32x4*)(o12W + (t+256)*8), w1b = *(const f32x4*)(o12W + (t+256)*8 + 4);
  float pa[8];
  for(int r=0;r<4;r++){ pa[r]   = x0*w0a[r] + x1*w1a[r];
                        pa[4+r] = x0*w0b[r] + x1*w1b[r]; }
  for(int o=32;o>=1;o>>=1) for(int k=0;k<8;k++) pa[k] += __shfl_down(pa[k],o);
  if((t&63)==0) for(int k=0;k<8;k++) red[w][k] = pa[k];
  __syncthreads();
  if(t<8){
    float tot = red[0][t]+red[1][t]+red[2][t]+red[3][t] + o12b[t];
    if(t<4) o1[row*4+t] = tot; else o2[row*4+(t-4)] = tot;
  }
}

// ---------------- K5: p1 = p + outer(o1[i],o2[j]) @ o3_W + o3_b  (all fp32) ----------------
__global__ __launch_bounds__(256) void k5_p1(const float* __restrict__ p,
                                             const float* __restrict__ o3W,
                                             const float* __restrict__ o3b,
                                             const float* __restrict__ o1,
                                             const float* __restrict__ o2,
                                             float* __restrict__ p1){
  __shared__ float w_s[2048];
  __shared__ float b_s[128];
  int t = threadIdx.x;
  for(int r=0;r<8;r++) w_s[t*8+r] = o3W[t*8+r];
  if(t<128) b_s[t] = o3b[t];
  __syncthreads();
  int g = blockIdx.x*16 + (t>>4);
  int e0 = (t&15)*8;
  int bb = g>>16, ii = (g>>8)&255, jj = g&255;
  const float* o1p = o1 + (bb*256+ii)*4;
  const float* o2p = o2 + (bb*256+jj)*4;
  float c[16];
  for(int h=0;h<4;h++) for(int g2=0;g2<4;g2++) c[h*4+g2] = o1p[h]*o2p[g2];
  f32x4 pv0 = *(const f32x4*)(p + (long)g*128 + e0);
  f32x4 pv1 = *(const f32x4*)(p + (long)g*128 + e0 + 4);
  float acc[8];
  for(int r=0;r<4;r++){ acc[r] = pv0[r] + b_s[e0+r]; acc[4+r] = pv1[r] + b_s[e0+4+r]; }
  for(int m=0;m<16;m++){
    const float* wr = &w_s[m*128 + e0];
    for(int r=0;r<8;r++) acc[r] += c[m]*wr[r];
  }
  f32x4 s0, s1;
  for(int r=0;r<4;r++){ s0[r] = acc[r]; s1[r] = acc[4+r]; }
  *(f32x4*)(p1 + (long)g*128 + e0)     = s0;
  *(f32x4*)(p1 + (long)g*128 + e0 + 4) = s1;
}

// ---------------- LN stage: 64 contiguous rows of 128 (fp32 src) -> bf16 LDS tile(s) ----------------
DI void ln_stage64(const float* __restrict__ psrc,
                   const float* __restrict__ s2,
                   const float* __restrict__ b2,
                   unsigned short* pnh, unsigned short* pnl, int t){
  int lr = t>>2, qt = t&3, e0 = qt*32;
  const float* pr = psrc + lr*128 + e0;
  float v[32];
  for(int c=0;c<8;c++){ f32x4 u = *(const f32x4*)(pr + c*4); for(int r=0;r<4;r++) v[c*4+r] = u[r]; }
  float s = 0.f, sq = 0.f;
  for(int k=0;k<32;k++){ s += v[k]; sq += v[k]*v[k]; }
  s  += __shfl_xor(s,1);  s  += __shfl_xor(s,2);
  sq += __shfl_xor(sq,1); sq += __shfl_xor(sq,2);
  float m = s*(1.f/128.f);
  float rstd = rsqrtf(sq*(1.f/128.f) - m*m + 1e-5f);
  for(int c=0;c<8;c++){
    f32x4 sv = *(const f32x4*)(s2 + e0 + c*4), bv = *(const f32x4*)(b2 + e0 + c*4);
    us4 vh, vl;
    for(int r=0;r<4;r++){
      float val = (v[c*4+r]-m)*rstd*sv[r] + bv[r];
      unsigned short h = f2b(val);
      vh[r] = h; vl[r] = f2b(val - b2f(h));
    }
    *(us4*)&pnh[lr*136 + e0 + c*4] = vh;
    if(pnl) *(us4*)&pnl[lr*136 + e0 + c*4] = vl;
  }
}

// ---------------- K7a: tt = LN(p1,en2)@t_W + t_b ; per-block reduced partials (NO atomics) ----------------
// block = 8x8 (ii x jj) tile; a_part[bb][iig][jj][4], bs_part[bb][jjt][ii][4]
__global__ __launch_bounds__(256) void k7a_tt(const float* __restrict__ p1,
                                              const float* __restrict__ en2s,
                                              const float* __restrict__ en2b,
                                              const unsigned short* __restrict__ tWT,
                                              const float* __restrict__ tb,
                                              const int* __restrict__ am,
                                              float* __restrict__ a_part,
                                              float* __restrict__ bs_part){
  __shared__ __align__(16) unsigned short pn[64*136];
  __shared__ float sga[64][4];
  __shared__ float sgb[64][4];
  int t = threadIdx.x;
  int jjt = blockIdx.x & 31, iig = (blockIdx.x>>5) & 31, bb = blockIdx.x>>10;
  { // LN stage over the 8x8 strip tile: row lr -> (di=lr>>3, dj=lr&7)
    int lr = t>>2, qt = t&3, e0 = qt*32;
    int di = lr>>3, dj = lr&7;
    long g = (long)bb*65536 + (iig*8+di)*256 + (jjt*8+dj);
    const float* pr = p1 + g*128 + e0;
    float v[32];
    for(int c=0;c<8;c++){ f32x4 u = *(const f32x4*)(pr + c*4); for(int r=0;r<4;r++) v[c*4+r] = u[r]; }
    float s = 0.f, sq = 0.f;
    for(int k=0;k<32;k++){ s += v[k]; sq += v[k]*v[k]; }
    s  += __shfl_xor(s,1);  s  += __shfl_xor(s,2);
    sq += __shfl_xor(sq,1); sq += __shfl_xor(sq,2);
    float m = s*(1.f/128.f);
    float rstd = rsqrtf(sq*(1.f/128.f) - m*m + 1e-5f);
    for(int c=0;c<8;c++){
      f32x4 sv = *(const f32x4*)(en2s + e0 + c*4), bv = *(const f32x4*)(en2b + e0 + c*4);
      us4 ov;
      for(int r=0;r<4;r++) ov[r] = f2b((v[c*4+r]-m)*rstd*sv[r] + bv[r]);
      *(us4*)&pn[lr*136 + e0 + c*4] = ov;
    }
  }
  __syncthreads();
  int w = t>>6, lane = t&63, l15 = lane&15, q = lane>>4;
  f32x4 acc = (f32x4){0.f,0.f,0.f,0.f};
  for(int kt=0;kt<4;kt++){
    s16x8 bf = *(const s16x8*)&pn[(w*16+l15)*136 + kt*32 + q*8];
    s16x8 af = *(const s16x8*)(tWT + (kt*64 + lane)*8);
    acc = MFMA(af, bf, acc);
  }
  f32x4 tb4 = *(const f32x4*)(tb + q*4);
  for(int r=0;r<4;r++) acc[r] += tb4[r];
  int rloc = w*16 + l15;
  int di = rloc>>3, dj = rloc&7;
  int msk = am[(bb*256 + iig*8+di)*256 + jjt*8+dj];
  float pr4[4];
  for(int r=0;r<4;r++) pr4[r] = __shfl_xor(acc[r], 16);
  if(q==0){      for(int r=0;r<4;r++) sga[rloc][r] = msk ? sigmf(acc[r]*pr4[r]) : 0.f; }
  else if(q==2){ for(int r=0;r<4;r++) sgb[rloc][r] = msk ? sigmf(acc[r]*pr4[r]) : 0.f; }
  __syncthreads();
  if(t < 32){
    int djr = t>>2, r = t&3;
    float s = 0.f;
    for(int d=0;d<8;d++) s += sga[d*8+djr][r];
    a_part[(((long)bb*32+iig)*256 + jjt*8+djr)*4 + r] = s;
  } else if(t < 64){
    int dir = (t-32)>>2, r = t&3;
    float s = 0.f;
    for(int d=0;d<8;d++) s += sgb[dir*8+d][r];
    bs_part[(((long)bb*32+jjt)*256 + iig*8+dir)*4 + r] = s;
  }
}

// ---------------- K6b: reduce 32 partial groups; A2 = a@t6_W ; Bs2 = bsum@t6_W + t6_b ----------------
__global__ __launch_bounds__(128) void k6b(const float* __restrict__ a_part,
                                           const float* __restrict__ bs_part,
                                           const float* __restrict__ t6W,
                                           const float* __restrict__ t6b,
                                           float* __restrict__ A2, float* __restrict__ Bs2){
  int d = blockIdx.x;          // bb*256 + row
  int bb = d>>8, rw = d&255;
  int e = threadIdx.x;
  __shared__ float as[4], bsr[4];
  if(e < 4){
    float s = 0.f;
    for(int g=0;g<32;g++) s += a_part[(((long)bb*32+g)*256 + rw)*4 + e];
    as[e] = s;
  } else if(e < 8){
    int r = e-4;
    float s = 0.f;
    for(int g=0;g<32;g++) s += bs_part[(((long)bb*32+g)*256 + rw)*4 + r];
    bsr[r] = s;
  }
  __syncthreads();
  float sa = 0.f, sb = 0.f;
  for(int h=0;h<4;h++){
    float wv = t6W[h*128+e];
    sa += as[h]*wv;
    sb += bsr[h]*wv;
  }
  A2[d*128+e]  = sa;
  Bs2[d*128+e] = sb + t6b[e];
}

// ---------------- K7b: t5 = LN(p1,en2)@t5_W + t5_b (split) ; p2 = p1 + sigmoid(...) ----------------
__global__ __launch_bounds__(256) void k7b_p2(float* __restrict__ dp,
                                              const float* __restrict__ en2s,
                                              const float* __restrict__ en2b,
                                              const unsigned short* __restrict__ t5Wh,
                                              const unsigned short* __restrict__ t5Wl,
                                              const float* __restrict__ t5b,
                                              const float* __restrict__ A2,
                                              const float* __restrict__ Bs2,
                                              const int* __restrict__ am){
  __shared__ __align__(16) unsigned short pnh[64*136];
  __shared__ __align__(16) unsigned short pnl[64*136];
  int t = threadIdx.x;
  long gbase = (long)blockIdx.x*64;
  ln_stage64(dp + gbase*128, en2s, en2b, pnh, pnl, t);
  __syncthreads();
  int w = t>>6, lane = t&63, l15 = lane&15, q = lane>>4;
  for(int mtl=0;mtl<2;mtl++){
    int mtg = w*2 + mtl;
    s16x8 afh[4], afl[4];
    for(int kt=0;kt<4;kt++){
      int wi = ((mtg*4+kt)*64 + lane)*8;
      afh[kt] = *(const s16x8*)(t5Wh + wi);
      afl[kt] = *(const s16x8*)(t5Wl + wi);
    }
    int e0 = mtg*16 + q*4;
    f32x4 t5b4 = *(const f32x4*)(t5b + e0);
    for(int nt=0;nt<4;nt++){
      f32x4 acc = (f32x4){0.f,0.f,0.f,0.f};
      for(int kt=0;kt<4;kt++){
        s16x8 bh = *(const s16x8*)&pnh[(nt*16+l15)*136 + kt*32 + q*8];
        s16x8 bl = *(const s16x8*)&pnl[(nt*16+l15)*136 + kt*32 + q*8];
        acc = MFMA(afh[kt], bh, acc);
        acc = MFMA(afh[kt], bl, acc);
        acc = MFMA(afl[kt], bh, acc);
      }
      long g = gbase + nt*16 + l15;
      int bb = (int)(g>>16), ii = ((int)g>>8)&255, jj = (int)g&255;
      int msk = am[(bb*256+ii)*256 + jj];
      const float* A2p = A2 + (bb*256+jj)*128 + e0;
      const float* Bsp = Bs2 + (bb*256+ii)*128 + e0;
      f32x4 p1v = *(const f32x4*)(dp + g*128 + e0);
      f32x4 ov;
      for(int r=0;r<4;r++){
        float sg = 0.f;
        if(msk){
          float t56 = (acc[r] + t5b4[r]) * (A2p[r] + Bsp[r]);
          sg = sigmf(t56);
        }
        ov[r] = p1v[r] + sg;
      }
      *(f32x4*)(dp + g*128 + e0) = ov;
    }
  }
}

// ---------------- K8: p3 = p2 + gelu(LN(p2,en3)@effn1+b)@effn2 + b  (p fp32) ----------------
__global__ __launch_bounds__(256) void k8_effn(float* __restrict__ dp,
                                               const float* __restrict__ en3s,
                                               const float* __restrict__ en3b,
                                               const unsigned short* __restrict__ W1T,
                                               const float* __restrict__ b1,
                                               const unsigned short* __restrict__ W2T,
                                               const float* __restrict__ b2){
  __shared__ __align__(16) unsigned short pn3[32*136];
  __shared__ __align__(16) unsigned short hT[32*520];
  int t = threadIdx.x;
  long base = (long)blockIdx.x*32;
  { // phase A: LN(p2, en3) -> pn3 tile
    int lr = t>>3, oct = t&7, e0 = oct*16;
    const float* pr = dp + (base+lr)*128 + e0;
    float v[16];
    for(int c=0;c<4;c++){ f32x4 u = *(const f32x4*)(pr + c*4); for(int r=0;r<4;r++) v[c*4+r] = u[r]; }
    float s = 0.f, sq = 0.f;
    for(int k=0;k<16;k++){ s += v[k]; sq += v[k]*v[k]; }
    s  += __shfl_xor(s,1);  s  += __shfl_xor(s,2);  s  += __shfl_xor(s,4);
    sq += __shfl_xor(sq,1); sq += __shfl_xor(sq,2); sq += __shfl_xor(sq,4);
    float m = s*(1.f/128.f);
    float rstd = rsqrtf(sq*(1.f/128.f) - m*m + 1e-5f);
    for(int c=0;c<4;c++){
      f32x4 sv = *(const f32x4*)(en3s + e0 + c*4), bv = *(const f32x4*)(en3b + e0 + c*4);
      us4 ov;
      for(int r=0;r<4;r++) ov[r] = f2b((v[c*4+r]-m)*rstd*sv[r] + bv[r]);
      *(us4*)&pn3[lr*136 + e0 + c*4] = ov;
    }
  }
  __syncthreads();
  int w = t>>6, lane = t&63, l15 = lane&15, q = lane>>4;
  { // GEMM1: hT = gelu(W1T * pn3^T + b1)
    s16x8 bfr[2][4];
    for(int nt=0;nt<2;nt++) for(int kt=0;kt<4;kt++)
      bfr[nt][kt] = *(const s16x8*)&pn3[(nt*16+l15)*136 + kt*32 + q*8];
    for(int mtl=0;mtl<8;mtl++){
      int mtg = w*8 + mtl;
      s16x8 af[4];
      for(int kt=0;kt<4;kt++) af[kt] = *(const s16x8*)(W1T + ((mtg*4+kt)*64 + lane)*8);
      int col0 = mtg*16 + q*4;
      f32x4 bb = *(const f32x4*)(b1 + col0);
      for(int nt=0;nt<2;nt++){
        f32x4 acc = (f32x4){0.f,0.f,0.f,0.f};
        for(int kt=0;kt<4;kt++) acc = MFMA(af[kt], bfr[nt][kt], acc);
        us4 hv;
        for(int r=0;r<4;r++) hv[r] = f2b(geluf(acc[r] + bb[r]));
        *(us4*)&hT[(nt*16+l15)*520 + col0] = hv;
      }
    }
  }
  __syncthreads();
  { // GEMM2: out = p2 + W2T * hT^T + b2
    f32x4 acc2[2][2];
    for(int a=0;a<2;a++) for(int n=0;n<2;n++) acc2[a][n] = (f32x4){0.f,0.f,0.f,0.f};
    for(int kt=0;kt<16;kt++){
      s16x8 bfr[2];
      for(int nt=0;nt<2;nt++) bfr[nt] = *(const s16x8*)&hT[(nt*16+l15)*520 + kt*32 + q*8];
      for(int mtl=0;mtl<2;mtl++){
        int m2 = w*2 + mtl;
        s16x8 af = *(const s16x8*)(W2T + ((m2*16+kt)*64 + lane)*8);
        for(int nt=0;nt<2;nt++) acc2[mtl][nt] = MFMA(af, bfr[nt], acc2[mtl][nt]);
      }
    }
    for(int mtl=0;mtl<2;mtl++){
      int m2 = w*2 + mtl;
      int col0 = m2*16 + q*4;
      f32x4 bb = *(const f32x4*)(b2 + col0);
      for(int nt=0;nt<2;nt++){
        long g = base + nt*16 + l15;
        f32x4 p2v = *(const f32x4*)(dp + g*128 + col0);
        f32x4 ov;
        for(int r=0;r<4;r++) ov[r] = p2v[r] + acc2[mtl][nt][r] + bb[r];
        *(f32x4*)(dp + g*128 + col0) = ov;
      }
    }
  }
}

extern "C" void kernel_launch(void* const* d_in, const int* in_sizes, int n_in,
                              void* d_out, int out_size, void* d_ws, size_t ws_size,
                              hipStream_t stream) {
  const float* x      = (const float*)d_in[0];
  const float* p      = (const float*)d_in[1];
  const int*   am     = (const int*)d_in[2];
  const float* nffn1W = (const float*)d_in[7];
  const float* nffn1b = (const float*)d_in[8];
  const float* nffn2W = (const float*)d_in[9];
  const float* nffn2b = (const float*)d_in[10];
  const float* o12W   = (const float*)d_in[11];
  const float* o12b   = (const float*)d_in[12];
  const float* o3W    = (const float*)d_in[13];
  const float* o3b    = (const float*)d_in[14];
  const float* tW     = (const float*)d_in[15];
  const float* tb     = (const float*)d_in[16];
  const float* t5W    = (const float*)d_in[17];
  const float* t5b    = (const float*)d_in[18];
  const float* t6W    = (const float*)d_in[19];
  const float* t6b    = (const float*)d_in[20];
  const float* e1W    = (const float*)d_in[21];
  const float* e1b    = (const float*)d_in[22];
  const float* e2W    = (const float*)d_in[23];
  const float* e2b    = (const float*)d_in[24];
  const float* n2s    = (const float*)d_in[27];
  const float* n2b    = (const float*)d_in[28];
  const float* en1s   = (const float*)d_in[29];
  const float* en1b   = (const float*)d_in[30];
  const float* en2s   = (const float*)d_in[31];
  const float* en2b   = (const float*)d_in[32];
  const float* en3s   = (const float*)d_in[33];
  const float* en3b   = (const float*)d_in[34];

  float* ox  = (float*)d_out;            // x out: 262144 f32
  float* opx = (float*)d_out + 262144;   // p out: 8388608 f32

  char* ws = (char*)d_ws;
  float* o1w    = (float*)(ws + 16384);    // 2048 f32
  float* o2w    = (float*)(ws + 24576);    // 2048 f32
  float* A2     = (float*)(ws + 32768);    // 65536 f32
  float* Bs2    = (float*)(ws + 294912);   // 65536 f32
  unsigned short* xnh = (unsigned short*)(ws + 557056);    // 262144 bf16
  unsigned short* xnl = (unsigned short*)(ws + 1081344);   // 262144 bf16
  unsigned short* h1h = (unsigned short*)(ws + 1605632);   // 1048576 bf16
  unsigned short* h1l = (unsigned short*)(ws + 3702784);   // 1048576 bf16
  unsigned short* tWT  = (unsigned short*)(ws + 5799936);  // 2048 bf16
  unsigned short* t5Wh = (unsigned short*)(ws + 5804032);  // 16384 bf16
  unsigned short* t5Wl = (unsigned short*)(ws + 5836800);  // 16384 bf16
  unsigned short* W1T  = (unsigned short*)(ws + 5869568);  // 65536 bf16 (effn1)
  unsigned short* W2T  = (unsigned short*)(ws + 6000640);  // 65536 bf16 (effn2)
  unsigned short* n1h  = (unsigned short*)(ws + 6131712);  // 1048576 bf16
  unsigned short* n1l  = (unsigned short*)(ws + 8228864);  // 1048576 bf16
  unsigned short* n2h  = (unsigned short*)(ws + 10326016); // 1048576 bf16
  unsigned short* n2l  = (unsigned short*)(ws + 12423168); // 1048576 bf16
  float* a_part  = (float*)(ws + 14520320);  // 65536 f32 (2 x 32 x 256 x 4)
  float* bs_part = (float*)(ws + 14782464);  // 65536 f32

  k_repack <<<1,   256, 0, stream>>>(tW,  tWT,  16,  2, 256);
  k_repack2<<<8,   256, 0, stream>>>(t5W, t5Wh, t5Wl, 128, 2, 2048);
  k_repack <<<32,  256, 0, stream>>>(e1W, W1T,  512, 2, 8192);
  k_repack <<<32,  256, 0, stream>>>(e2W, W2T,  128, 4, 8192);
  k_repack2<<<512, 256, 0, stream>>>(nffn1W, n1h, n1l, 2048, 4, 131072);
  k_repack2<<<512, 256, 0, stream>>>(nffn2W, n2h, n2l, 512,  6, 131072);

  k1_ln<<<512, 256, 0, stream>>>(x, n2s, n2b, xnh, xnl);
  k2_ffn1<<<dim3(16,8), 256, 0, stream>>>(xnh, xnl, n1h, n1l, nffn1b, h1h, h1l);
  k3_ffn2<<<dim3(16,8), 256, 0, stream>>>(h1h, h1l, n2h, n2l, nffn2b, x, ox);
  k4_o12<<<512, 256, 0, stream>>>(ox, en1s, en1b, o12W, o12b, o1w, o2w);

  k5_p1<<<8192, 256, 0, stream>>>(p, o3W, o3b, o1w, o2w, opx);
  k7a_tt<<<2048, 256, 0, stream>>>(opx, en2s, en2b, tWT, tb, am, a_part, bs_part);
  k6b<<<512, 128, 0, stream>>>(a_part, bs_part, t6W, t6b, A2, Bs2);
  k7b_p2<<<2048, 256, 0, stream>>>(opx, en2s, en2b, t5Wh, t5Wl, t5b, A2, Bs2, am);
  k8_effn<<<4096, 256, 0, stream>>>(opx, en3s, en3b, W1T, e1b, W2T, e2b);
}